// Round 12
// baseline (103.867 us; speedup 1.0000x reference)
//
#include <hip/hip_runtime.h>
#include <hip/hip_bf16.h>

typedef unsigned short u16;
typedef unsigned short ushort8v __attribute__((ext_vector_type(8)));
typedef __bf16 bf16x8 __attribute__((ext_vector_type(8)));
typedef float f32x4 __attribute__((ext_vector_type(4)));

#define NB 16   // batch
#define NK 32   // K slices
#define ND 256  // D
#define NL 256  // L1 == L2

__device__ __forceinline__ u16 f2bf(float f) {
    __hip_bfloat16 h = __float2bfloat16(f);
    return __builtin_bit_cast(u16, h);
}

// async global->LDS, 16B per lane; lds dst = wave-uniform base + lane*16
__device__ __forceinline__ void gload_lds16(const void* g, void* l) {
    __builtin_amdgcn_global_load_lds(
        (const __attribute__((address_space(1))) unsigned int*)g,
        (__attribute__((address_space(3))) unsigned int*)l, 16, 0, 0);
}

// Fragment-order layout for a 256x256 matrix X[r][c] (c = contraction dim):
//   buf[((rt*8 + ct)*64 + lane)*8 + (c&7)], rt=r>>4, ct=c>>5,
//   lane = (r&15) | (((c>>3)&3)<<4)
// => a wave's 16x16x32 MFMA fragment is 1 KiB contiguous; coalesced dwordx4 loads.

// ---------------- fused prep ----------------
// blocks 0..4095    : f32 -> frag-order bf16 converts (x1 / x2 / W)
// blocks 4096..4223 : lin1/lin2 with LDS-staged COALESCED reads (128 blocks:
//                     16 b x 8 l-tiles of 32 rows), replacing the uncoalesced
//                     32-block MFMA version (R2-style stride-1KB reads).
__global__ void prep_kernel(const float* __restrict__ x1, const float* __restrict__ x2,
                            const float* __restrict__ W, const float* __restrict__ V,
                            const float* __restrict__ bb,
                            u16* __restrict__ x1f, u16* __restrict__ x2f, u16* __restrict__ Wf,
                            float* __restrict__ lin1, float* __restrict__ lin2) {
    __shared__ float xs[32 * 260];   // 33 KiB, padded stride (4-way max conflicts)
    int bid = blockIdx.x;
    int tid = threadIdx.x;
    if (bid < 4096) {
        const float* src; u16* dst; long f4;
        if (bid < 1024)      { src = x1; dst = x1f; f4 = (long)bid * 256 + tid; }
        else if (bid < 2048) { src = x2; dst = x2f; f4 = (long)(bid - 1024) * 256 + tid; }
        else                 { src = W;  dst = Wf;  f4 = (long)(bid - 2048) * 256 + tid; }
        long idx = f4 << 2;
        int mat = (int)(idx >> 16);
        int r = (int)((idx >> 8) & 255);
        int c = (int)(idx & 255);
        float4 v = ((const float4*)src)[f4];
        ushort4 o;
        o.x = f2bf(v.x); o.y = f2bf(v.y); o.z = f2bf(v.z); o.w = f2bf(v.w);
        int rt = r >> 4, ct = c >> 5;
        int lane = (r & 15) | (((c >> 3) & 3) << 4);
        long off = ((long)mat << 16) + (((rt << 3) + ct) << 9) + (lane << 3) + (c & 7);
        *(ushort4*)(dst + off) = o;
        return;
    }
    // ---- lin blocks: bid2 = b*8 + t8; rows l0..l0+31
    int bid2 = bid - 4096;
    int b  = bid2 >> 3;
    int l0 = (bid2 & 7) << 5;
#pragma unroll
    for (int pass = 0; pass < 2; ++pass) {
        const float* xp = (pass ? x2 : x1) + ((long)b << 16) + ((long)l0 << 8);
        // stage 32 rows x 256 f32, fully coalesced
#pragma unroll
        for (int it = 0; it < 8; ++it) {
            int ch = (it << 8) + tid;       // 2048 float4 chunks
            int row = ch >> 6;
            int col = ch & 63;
            float4 v = *(const float4*)(xp + (row << 8) + (col << 2));
            *(float4*)(xs + row * 260 + (col << 2)) = v;
        }
        __syncthreads();
        int l = tid & 31, kg = tid >> 5;    // 8 k-groups x 4 k
        float s[4] = {0.f, 0.f, 0.f, 0.f};
        for (int d4 = 0; d4 < 64; ++d4) {
            float4 x = *(const float4*)(xs + l * 260 + (d4 << 2));
#pragma unroll
            for (int ki = 0; ki < 4; ++ki) {
                float4 vv = *(const float4*)(V + ((long)(((kg << 2) + ki) << 9)) + (pass << 8) + (d4 << 2));
                s[ki] += x.x * vv.x + x.y * vv.y + x.z * vv.z + x.w * vv.w;
            }
        }
        float* dst = pass ? lin2 : lin1;
#pragma unroll
        for (int ki = 0; ki < 4; ++ki) {
            int k = (kg << 2) + ki;
            float add = pass ? 0.f : bb[k];
            dst[((long)(b * NK + k) << 8) + l0 + l] = s[ki] + add;
        }
        __syncthreads();   // before restaging xs with x2
    }
}

// ---------------- main fused kernel (R9 structure, byte-identical — proven best) ----
__launch_bounds__(512, 6)
__global__ void ntn_main(const u16* __restrict__ x1f, const u16* __restrict__ x2f,
                         const u16* __restrict__ Wf,
                         const float* __restrict__ lin1, const float* __restrict__ lin2,
                         float* __restrict__ out) {
    __shared__ __align__(16) char ldsRaw[32768];   // x2 stage -> U^T -> epilogue chunks

    // supertile decode: 128-block supertiles of 8k x 4b x 4mq per XCD slot
    int bid = blockIdx.x;
    int xcd   = bid & 7;
    int j     = bid >> 3;
    int slot  = j >> 7;
    int inner = j & 127;
    int st    = (slot << 3) | xcd;     // 0..15
    int kg = st >> 2, bg = st & 3;
    int k  = (kg << 3) | (inner >> 4);
    int b  = (bg << 2) | ((inner >> 2) & 3);
    int mq = inner & 3;

    int tid  = threadIdx.x;
    int lane = tid & 63;
    int wid  = tid >> 6;
    int lrow = lane & 15;
    int j4   = (lane >> 4) << 2;

    // ---- async stage x2 m-quarter: 32 chunks of 1 KiB (frag-order is linear)
    {
        const char* src = (const char*)(x2f + ((long)b << 16) + ((long)mq << 14));
#pragma unroll
        for (int it = 0; it < 4; ++it) {
            int chunk = (it << 3) + wid;
            gload_lds16(src + (chunk << 10) + (lane << 4), ldsRaw + (chunk << 10));
        }
    }

    f32x4 acc[4][2];
    const f32x4 fz = {0.f, 0.f, 0.f, 0.f};
#pragma unroll
    for (int i = 0; i < 4; ++i) { acc[i][0] = fz; acc[i][1] = fz; }

    __syncthreads();   // x2 staged

    // ================= phase A: U^T[m'][d] =================
    {
        int wrA = wid >> 1;   // d-dim 0..3 (4 d-tiles each)
        int wcA = wid & 1;    // m-dim 0..1 (2 m-tiles each)
        const u16* wp = Wf + ((long)k << 16);
#pragma unroll
        for (int et = 0; et < 8; ++et) {
            bf16x8 af[4], bfr[2];
#pragma unroll
            for (int lt = 0; lt < 4; ++lt)
                af[lt] = *(const bf16x8*)(wp + (((((wrA << 2) + lt) << 3) + et) << 9) + (lane << 3));
#pragma unroll
            for (int nt = 0; nt < 2; ++nt)
                bfr[nt] = *(const bf16x8*)(ldsRaw + ((((((wcA << 1) + nt) << 3) + et) << 10) + (lane << 4)));
#pragma unroll
            for (int nt = 0; nt < 2; ++nt)
#pragma unroll
                for (int lt = 0; lt < 4; ++lt)
                    acc[lt][nt] = __builtin_amdgcn_mfma_f32_16x16x32_bf16(af[lt], bfr[nt], acc[lt][nt], 0, 0, 0);
        }
    }
    __syncthreads();   // all x2 LDS reads done; safe to overwrite with U^T

    // ---- write U^T[m' 64][d 256] u16 LDS (rows 512 B), swizzle byte^=((m&7)<<4)
    {
        int wrA = wid >> 1;
        int wcA = wid & 1;
#pragma unroll
        for (int lt = 0; lt < 4; ++lt) {
            int d0 = (wrA << 6) + (lt << 4) + j4;
#pragma unroll
            for (int nt = 0; nt < 2; ++nt) {
                int m = (wcA << 5) + (nt << 4) + lrow;   // 0..63
                ushort4 pk;
                pk.x = f2bf(acc[lt][nt][0]);
                pk.y = f2bf(acc[lt][nt][1]);
                pk.z = f2bf(acc[lt][nt][2]);
                pk.w = f2bf(acc[lt][nt][3]);
                *(ushort4*)(ldsRaw + (m << 9) + ((d0 << 1) ^ ((m & 7) << 4))) = pk;
            }
        }
    }
    __syncthreads();

#pragma unroll
    for (int i = 0; i < 4; ++i) { acc[i][0] = fz; acc[i][1] = fz; }

    // ================= phase B: D[m 64][l 256]; wave wid owns l-tiles 2*wid,2*wid+1 ====
    {
        const u16* x1p = x1f + ((long)b << 16);
        int lk8 = (lane >> 4) << 3;
#pragma unroll
        for (int dt = 0; dt < 8; ++dt) {
            int d = (dt << 5) + lk8;
            bf16x8 am[4], xl[2];
#pragma unroll
            for (int mt = 0; mt < 4; ++mt) {
                int m = (mt << 4) + lrow;
                am[mt] = *(const bf16x8*)(ldsRaw + (m << 9) + ((d << 1) ^ ((m & 7) << 4)));
            }
#pragma unroll
            for (int lt = 0; lt < 2; ++lt)
                xl[lt] = *(const bf16x8*)(x1p + (((((wid << 1) + lt) << 3) + dt) << 9) + (lane << 3));
#pragma unroll
            for (int lt = 0; lt < 2; ++lt)
#pragma unroll
                for (int mt = 0; mt < 4; ++mt)
                    acc[mt][lt] = __builtin_amdgcn_mfma_f32_16x16x32_bf16(am[mt], xl[lt], acc[mt][lt], 0, 0, 0);
        }
    }
    __syncthreads();   // all U^T reads done; safe to overwrite as f32 chunk

    // ================= epilogue: +lin1+lin2, relu, LDS transpose, coalesced stores ====
    {
        const float* l1p = lin1 + (((long)(b * NK + k)) << 8);
        const float* l2p = lin2 + (((long)(b * NK + k)) << 8) + (mq << 6);
        float* outp = out + (((long)(b * NK + k)) << 16) + (mq << 6);

#pragma unroll
        for (int c = 0; c < 2; ++c) {
            if ((wid >> 2) == c) {
                float rb[2];
#pragma unroll
                for (int lt = 0; lt < 2; ++lt)
                    rb[lt] = l1p[(wid << 5) + (lt << 4) + lrow];
#pragma unroll
                for (int mt = 0; mt < 4; ++mt) {
                    int mcol = (mt << 4) + j4;
                    float4 l2v = *(const float4*)(l2p + mcol);
#pragma unroll
                    for (int lt = 0; lt < 2; ++lt) {
                        int row = ((wid & 3) << 5) + (lt << 4) + lrow;   // chunk-local l 0..127
                        f32x4 v;
                        v[0] = acc[mt][lt][0] + rb[lt] + l2v.x;
                        v[1] = acc[mt][lt][1] + rb[lt] + l2v.y;
                        v[2] = acc[mt][lt][2] + rb[lt] + l2v.z;
                        v[3] = acc[mt][lt][3] + rb[lt] + l2v.w;
                        v[0] = v[0] > 0.f ? v[0] : 0.f;
                        v[1] = v[1] > 0.f ? v[1] : 0.f;
                        v[2] = v[2] > 0.f ? v[2] : 0.f;
                        v[3] = v[3] > 0.f ? v[3] : 0.f;
                        *(f32x4*)(ldsRaw + (row << 8) + ((mcol << 2) ^ ((row & 7) << 4))) = v;
                    }
                }
            }
            __syncthreads();
            // stream chunk: 32 KiB = 512 threads x f32x4 x 4 iters; 256 B runs per row
#pragma unroll
            for (int it = 0; it < 4; ++it) {
                int g = (it << 9) + tid;
                int row = g >> 4;       // 0..127
                int c4  = g & 15;       // 16B block within 256B row
                f32x4 v = *(const f32x4*)(ldsRaw + (row << 8) + ((c4 << 4) ^ ((row & 7) << 4)));
                __builtin_nontemporal_store(v, (f32x4*)(outp + ((long)((c << 7) + row) << 8) + (c4 << 2)));
            }
            if (c == 0) __syncthreads();
        }
    }
}

extern "C" void kernel_launch(void* const* d_in, const int* in_sizes, int n_in,
                              void* d_out, int out_size, void* d_ws, size_t ws_size,
                              hipStream_t stream) {
    const float* x1 = (const float*)d_in[0];
    const float* x2 = (const float*)d_in[1];
    const float* W  = (const float*)d_in[2];
    const float* V  = (const float*)d_in[3];
    const float* bb = (const float*)d_in[4];
    float* out = (float*)d_out;

    char* ws = (char*)d_ws;
    u16*   x1f  = (u16*)(ws);                               // 2 MiB
    u16*   x2f  = (u16*)(ws + (2l << 20));                  // 2 MiB
    u16*   Wf   = (u16*)(ws + (4l << 20));                  // 4 MiB
    float* lin1 = (float*)(ws + (8l << 20));                // 512 KiB
    float* lin2 = (float*)(ws + (8l << 20) + (512l << 10)); // 512 KiB

    hipLaunchKernelGGL(prep_kernel, dim3(4224), dim3(256), 0, stream,
                       x1, x2, W, V, bb, x1f, x2f, Wf, lin1, lin2);
    hipLaunchKernelGGL(ntn_main, dim3(2048), dim3(512), 0, stream,
                       x1f, x2f, Wf, lin1, lin2, out);
}

// Round 13
// 70.666 us; speedup vs baseline: 1.4698x; 1.4698x over previous
//
#include <hip/hip_runtime.h>
#include <hip/hip_bf16.h>

typedef unsigned short u16;
typedef __bf16 bf16x8 __attribute__((ext_vector_type(8)));
typedef float f32x4 __attribute__((ext_vector_type(4)));

#define NB 16   // batch
#define NK 32   // K slices
#define ND 256  // D
#define NL 256  // L1 == L2

__device__ __forceinline__ u16 f2bf(float f) {
    __hip_bfloat16 h = __float2bfloat16(f);
    return __builtin_bit_cast(u16, h);
}

// async global->LDS, 16B per lane; lds dst = wave-uniform base + lane*16
__device__ __forceinline__ void gload_lds16(const void* g, void* l) {
    __builtin_amdgcn_global_load_lds(
        (const __attribute__((address_space(1))) unsigned int*)g,
        (__attribute__((address_space(3))) unsigned int*)l, 16, 0, 0);
}

// Fragment-order layout for a 256x256 matrix X[r][c] (c = contraction dim):
//   buf[((rt*8 + ct)*64 + lane)*8 + (c&7)], rt=r>>4, ct=c>>5,
//   lane = (r&15) | (((c>>3)&3)<<4)
// => a wave's 16x16x32 MFMA fragment is 1 KiB contiguous; coalesced dwordx4 loads.

// ---------------- prep: PURE coalesced f32 -> frag-order bf16 (no lin work) --------
__global__ void prep_kernel(const float* __restrict__ x1, const float* __restrict__ x2,
                            const float* __restrict__ W,
                            u16* __restrict__ x1f, u16* __restrict__ x2f, u16* __restrict__ Wf) {
    int bid = blockIdx.x;
    int tid = threadIdx.x;
    const float* src; u16* dst; long f4;
    if (bid < 1024)      { src = x1; dst = x1f; f4 = (long)bid * 256 + tid; }
    else if (bid < 2048) { src = x2; dst = x2f; f4 = (long)(bid - 1024) * 256 + tid; }
    else                 { src = W;  dst = Wf;  f4 = (long)(bid - 2048) * 256 + tid; }
    long idx = f4 << 2;
    int mat = (int)(idx >> 16);
    int r = (int)((idx >> 8) & 255);
    int c = (int)(idx & 255);
    float4 v = ((const float4*)src)[f4];
    ushort4 o;
    o.x = f2bf(v.x); o.y = f2bf(v.y); o.z = f2bf(v.z); o.w = f2bf(v.w);
    int rt = r >> 4, ct = c >> 5;
    int lane = (r & 15) | (((c >> 3) & 3) << 4);
    long off = ((long)mat << 16) + (((rt << 3) + ct) << 9) + (lane << 3) + (c & 7);
    *(ushort4*)(dst + off) = o;
}

// ---------------- main fused kernel (R9 structure + lin folding) ----------------
// grid: 2048 supertiled blocks (k,b,mq); 512 threads = 8 waves; 32 KiB + 256 B LDS.
// stage:  x2 m-quarter -> LDS (linear, global_load_lds w16)
// rlin:   r[m] = sum_e V2[k][e]*x2[m][e] + b[k]  (x2 from LDS, shfl-reduced -> rlin[64])
// phase A: U'[d][m] = sum_e W[k][d][e]*x2[b][m][e]; V1[k][d] added in f32 at U^T write
//          (folds lin1 into phase B's contraction: x1 . V1 emerges automatically)
// phase B: D[m][l] = U'^T . x1  (A from LDS swizzled, B frag-order global)
// epilogue: + rlin[m], relu, LDS-transpose chunks -> full-line nontemporal stores.
__launch_bounds__(512, 6)
__global__ void ntn_main(const u16* __restrict__ x1f, const u16* __restrict__ x2f,
                         const u16* __restrict__ Wf,
                         const float* __restrict__ V, const float* __restrict__ bb,
                         float* __restrict__ out) {
    __shared__ __align__(16) char ldsRaw[32768];   // x2 stage -> U'^T -> epilogue chunks
    __shared__ float rlin[64];                     // r[m] = lin2 + b

    // supertile decode: 128-block supertiles of 8k x 4b x 4mq per XCD slot
    int bid = blockIdx.x;
    int xcd   = bid & 7;
    int j     = bid >> 3;
    int slot  = j >> 7;
    int inner = j & 127;
    int st    = (slot << 3) | xcd;     // 0..15
    int kg = st >> 2, bg = st & 3;
    int k  = (kg << 3) | (inner >> 4);
    int b  = (bg << 2) | ((inner >> 2) & 3);
    int mq = inner & 3;

    int tid  = threadIdx.x;
    int lane = tid & 63;
    int wid  = tid >> 6;
    int lrow = lane & 15;
    int j4   = (lane >> 4) << 2;

    // ---- async stage x2 m-quarter: 32 chunks of 1 KiB (frag-order is linear)
    {
        const char* src = (const char*)(x2f + ((long)b << 16) + ((long)mq << 14));
#pragma unroll
        for (int it = 0; it < 4; ++it) {
            int chunk = (it << 3) + wid;
            gload_lds16(src + (chunk << 10) + (lane << 4), ldsRaw + (chunk << 10));
        }
    }

    float bk = bb[k];
    f32x4 acc[4][2];
    const f32x4 fz = {0.f, 0.f, 0.f, 0.f};
#pragma unroll
    for (int i = 0; i < 4; ++i) { acc[i][0] = fz; acc[i][1] = fz; }

    __syncthreads();   // x2 staged

    // ---- rlin: r[m] = sum_e V2[e]*x2[m][e] + b[k]; 8 threads per m, shfl-reduce
    {
        int ml = tid >> 3;          // local m 0..63
        int et = tid & 7;           // e-tile (32 e's)
        const float* v2p = V + ((long)k << 9) + 256 + (et << 5);
        float sum = 0.f;
#pragma unroll
        for (int eg = 0; eg < 4; ++eg) {
            int lp = (ml & 15) | (eg << 4);
            bf16x8 xv = *(const bf16x8*)(ldsRaw + ((((ml >> 4) << 3) + et) << 10) + (lp << 4));
            float4 va = *(const float4*)(v2p + (eg << 3));
            float4 vb = *(const float4*)(v2p + (eg << 3) + 4);
            sum += (float)xv[0] * va.x + (float)xv[1] * va.y + (float)xv[2] * va.z + (float)xv[3] * va.w
                 + (float)xv[4] * vb.x + (float)xv[5] * vb.y + (float)xv[6] * vb.z + (float)xv[7] * vb.w;
        }
        sum += __shfl_xor(sum, 1);
        sum += __shfl_xor(sum, 2);
        sum += __shfl_xor(sum, 4);
        if ((tid & 7) == 0) rlin[ml] = sum + bk;
    }

    // ================= phase A: U'^T[m'][d] =================
    {
        int wrA = wid >> 1;   // d-dim 0..3 (4 d-tiles each)
        int wcA = wid & 1;    // m-dim 0..1 (2 m-tiles each)
        const u16* wp = Wf + ((long)k << 16);
#pragma unroll
        for (int et = 0; et < 8; ++et) {
            bf16x8 af[4], bfr[2];
#pragma unroll
            for (int lt = 0; lt < 4; ++lt)
                af[lt] = *(const bf16x8*)(wp + (((((wrA << 2) + lt) << 3) + et) << 9) + (lane << 3));
#pragma unroll
            for (int nt = 0; nt < 2; ++nt)
                bfr[nt] = *(const bf16x8*)(ldsRaw + ((((((wcA << 1) + nt) << 3) + et) << 10) + (lane << 4)));
#pragma unroll
            for (int nt = 0; nt < 2; ++nt)
#pragma unroll
                for (int lt = 0; lt < 4; ++lt)
                    acc[lt][nt] = __builtin_amdgcn_mfma_f32_16x16x32_bf16(af[lt], bfr[nt], acc[lt][nt], 0, 0, 0);
        }
    }
    __syncthreads();   // all x2 LDS reads (incl. rlin pass) done; safe to overwrite

    // ---- write U'^T[m' 64][d 256] u16 (rows 512 B), swizzle byte^=((m&7)<<4)
    //      V1[k][d] added in f32 BEFORE the bf16 round (lin1 fold)
    {
        int wrA = wid >> 1;
        int wcA = wid & 1;
        const float* v1base = V + ((long)k << 9);
#pragma unroll
        for (int lt = 0; lt < 4; ++lt) {
            int d0 = (wrA << 6) + (lt << 4) + j4;
            float4 v1q = *(const float4*)(v1base + d0);
#pragma unroll
            for (int nt = 0; nt < 2; ++nt) {
                int m = (wcA << 5) + (nt << 4) + lrow;   // 0..63
                ushort4 pk;
                pk.x = f2bf(acc[lt][nt][0] + v1q.x);
                pk.y = f2bf(acc[lt][nt][1] + v1q.y);
                pk.z = f2bf(acc[lt][nt][2] + v1q.z);
                pk.w = f2bf(acc[lt][nt][3] + v1q.w);
                *(ushort4*)(ldsRaw + (m << 9) + ((d0 << 1) ^ ((m & 7) << 4))) = pk;
            }
        }
    }
    __syncthreads();

#pragma unroll
    for (int i = 0; i < 4; ++i) { acc[i][0] = fz; acc[i][1] = fz; }

    // ================= phase B: D[m 64][l 256]; wave wid owns l-tiles 2*wid,2*wid+1 ====
    {
        const u16* x1p = x1f + ((long)b << 16);
        int lk8 = (lane >> 4) << 3;
#pragma unroll
        for (int dt = 0; dt < 8; ++dt) {
            int d = (dt << 5) + lk8;
            bf16x8 am[4], xl[2];
#pragma unroll
            for (int mt = 0; mt < 4; ++mt) {
                int m = (mt << 4) + lrow;
                am[mt] = *(const bf16x8*)(ldsRaw + (m << 9) + ((d << 1) ^ ((m & 7) << 4)));
            }
#pragma unroll
            for (int lt = 0; lt < 2; ++lt)
                xl[lt] = *(const bf16x8*)(x1p + (((((wid << 1) + lt) << 3) + dt) << 9) + (lane << 3));
#pragma unroll
            for (int lt = 0; lt < 2; ++lt)
#pragma unroll
                for (int mt = 0; mt < 4; ++mt)
                    acc[mt][lt] = __builtin_amdgcn_mfma_f32_16x16x32_bf16(am[mt], xl[lt], acc[mt][lt], 0, 0, 0);
        }
    }
    __syncthreads();   // all U'^T reads done; safe to overwrite as f32 chunk

    // ================= epilogue: + rlin[m], relu, LDS transpose, coalesced stores ====
    {
        float* outp = out + (((long)(b * NK + k)) << 16) + (mq << 6);

#pragma unroll
        for (int c = 0; c < 2; ++c) {
            if ((wid >> 2) == c) {
#pragma unroll
                for (int mt = 0; mt < 4; ++mt) {
                    int mcol = (mt << 4) + j4;
                    float4 rv = *(const float4*)(rlin + mcol);
#pragma unroll
                    for (int lt = 0; lt < 2; ++lt) {
                        int row = ((wid & 3) << 5) + (lt << 4) + lrow;   // chunk-local l 0..127
                        f32x4 v;
                        v[0] = acc[mt][lt][0] + rv.x;
                        v[1] = acc[mt][lt][1] + rv.y;
                        v[2] = acc[mt][lt][2] + rv.z;
                        v[3] = acc[mt][lt][3] + rv.w;
                        v[0] = v[0] > 0.f ? v[0] : 0.f;
                        v[1] = v[1] > 0.f ? v[1] : 0.f;
                        v[2] = v[2] > 0.f ? v[2] : 0.f;
                        v[3] = v[3] > 0.f ? v[3] : 0.f;
                        *(f32x4*)(ldsRaw + (row << 8) + ((mcol << 2) ^ ((row & 7) << 4))) = v;
                    }
                }
            }
            __syncthreads();
            // stream chunk: 32 KiB = 512 threads x f32x4 x 4 iters; 256 B runs per row
#pragma unroll
            for (int it = 0; it < 4; ++it) {
                int g = (it << 9) + tid;
                int row = g >> 4;       // 0..127
                int c4  = g & 15;       // 16B block within 256B row
                f32x4 v = *(const f32x4*)(ldsRaw + (row << 8) + ((c4 << 4) ^ ((row & 7) << 4)));
                __builtin_nontemporal_store(v, (f32x4*)(outp + ((long)((c << 7) + row) << 8) + (c4 << 2)));
            }
            if (c == 0) __syncthreads();
        }
    }
}

extern "C" void kernel_launch(void* const* d_in, const int* in_sizes, int n_in,
                              void* d_out, int out_size, void* d_ws, size_t ws_size,
                              hipStream_t stream) {
    const float* x1 = (const float*)d_in[0];
    const float* x2 = (const float*)d_in[1];
    const float* W  = (const float*)d_in[2];
    const float* V  = (const float*)d_in[3];
    const float* bb = (const float*)d_in[4];
    float* out = (float*)d_out;

    char* ws = (char*)d_ws;
    u16*   x1f  = (u16*)(ws);                               // 2 MiB
    u16*   x2f  = (u16*)(ws + (2l << 20));                  // 2 MiB
    u16*   Wf   = (u16*)(ws + (4l << 20));                  // 4 MiB

    hipLaunchKernelGGL(prep_kernel, dim3(4096), dim3(256), 0, stream,
                       x1, x2, W, x1f, x2f, Wf);
    hipLaunchKernelGGL(ntn_main, dim3(2048), dim3(512), 0, stream,
                       x1f, x2f, Wf, V, bb, out);
}